// Round 3
// baseline (1969.370 us; speedup 1.0000x reference)
//
#include <hip/hip_runtime.h>

typedef float v4f __attribute__((ext_vector_type(4)));

static constexpr float EPS = 1e-6f;

// DPP-based partial sum step: x += dpp_move(x); out-of-bounds lanes add 0.
#define DPP_ADD(x, ctrl, rmask)                                               \
  x += __builtin_bit_cast(float, __builtin_amdgcn_update_dpp(                 \
           0, __builtin_bit_cast(int, x), ctrl, rmask, 0xf, true))

// Full wave64 sum, 3 values interleaved (fills DPP hazard slots).
// After this, lane 63 holds each total.
#define WAVE_RED3(a, b, c)                                                    \
  do {                                                                        \
    DPP_ADD(a, 0x111, 0xf); DPP_ADD(b, 0x111, 0xf); DPP_ADD(c, 0x111, 0xf);  \
    DPP_ADD(a, 0x112, 0xf); DPP_ADD(b, 0x112, 0xf); DPP_ADD(c, 0x112, 0xf);  \
    DPP_ADD(a, 0x114, 0xf); DPP_ADD(b, 0x114, 0xf); DPP_ADD(c, 0x114, 0xf);  \
    DPP_ADD(a, 0x118, 0xf); DPP_ADD(b, 0x118, 0xf); DPP_ADD(c, 0x118, 0xf);  \
    DPP_ADD(a, 0x142, 0xa); DPP_ADD(b, 0x142, 0xa); DPP_ADD(c, 0x142, 0xa);  \
    DPP_ADD(a, 0x143, 0xc); DPP_ADD(b, 0x143, 0xc); DPP_ADD(c, 0x143, 0xc);  \
  } while (0)

#define WAVE_RED1(a)                                                          \
  do {                                                                        \
    DPP_ADD(a, 0x111, 0xf); DPP_ADD(a, 0x112, 0xf); DPP_ADD(a, 0x114, 0xf);  \
    DPP_ADD(a, 0x118, 0xf); DPP_ADD(a, 0x142, 0xa); DPP_ADD(a, 0x143, 0xc);  \
  } while (0)

__device__ __forceinline__ float bcast_lane63(float x) {
  return __builtin_bit_cast(
      float, __builtin_amdgcn_readlane(__builtin_bit_cast(int, x), 63));
}

#define GLL(idx, slot)                                                        \
  __builtin_amdgcn_global_load_lds(                                           \
      (const __attribute__((address_space(1))) void*)(hb + (size_t)(idx) * 64 + lane), \
      (__attribute__((address_space(3))) void*)&kring[(slot)][0], 4, 0, 0)

// BODY(t, Kc, Kn, K2):
//   Kc = broadcast k_t (consumed: M update), Kn = broadcast k_{t+1}
//   (consumed: dot), K2 = destination for broadcast k_{t+2} (next iter's Kn).
// Pipeline: global ring is 4 steps deep (issue t+6, wait vmcnt(4) -> k_{t+2}
// landed); LDS broadcast reads are issued one full step before consumption.
#define BODY(t, Kc, Kn, K2)                                                   \
  do {                                                                        \
    int _idx = (t) + 6;                                                       \
    if (_idx > LM1) _idx = LM1;                                               \
    GLL(_idx, ((t) + 6) & 7);                                                 \
    asm volatile("s_waitcnt vmcnt(4)" ::: "memory"); /* k_{t+2} in LDS */     \
    const float* _kb = &kring[((t) + 2) & 7][0];                              \
    float ks2 = _kb[lane];                                                    \
    {                                                                         \
      const v4f* _kv = (const v4f*)_kb;                                       \
      _Pragma("unroll")                                                       \
      for (int q = 0; q < 8; ++q) K2[q] = _kv[q]; /* early half */            \
    }                                                                         \
    __builtin_amdgcn_sched_barrier(0);                                        \
    /* per-lane delta-rule quantities */                                      \
    float u = fmaf(-vp, r, ksc);            /* u = k_t - vp/denom */          \
    float z = u * fmaf(s2, u, 2.0f * vp);   /* gate summand */                \
    float cp = ksc * ksn;                   /* -> k_t . k_{t+1} */            \
    float sp = ksn * ksn;                   /* -> |k_{t+1}|^2 */              \
    /* a = M_t . k_{t+1} from registers loaded LAST iteration */              \
    v4f ac0 = v4f{0.f, 0.f, 0.f, 0.f}, ac1 = ac0, ac2 = ac0, ac3 = ac0;      \
    _Pragma("unroll")                                                         \
    for (int q = 0; q < 4; ++q) {                                             \
      ac0 = __builtin_elementwise_fma(m4[4 * q + 0], Kn[4 * q + 0], ac0);     \
      ac1 = __builtin_elementwise_fma(m4[4 * q + 1], Kn[4 * q + 1], ac1);     \
      ac2 = __builtin_elementwise_fma(m4[4 * q + 2], Kn[4 * q + 2], ac2);     \
      ac3 = __builtin_elementwise_fma(m4[4 * q + 3], Kn[4 * q + 3], ac3);     \
    }                                                                         \
    WAVE_RED3(z, cp, sp);                                                     \
    v4f acs = (ac0 + ac1) + (ac2 + ac3);                                      \
    float a = (acs.x + acs.y) + (acs.z + acs.w);                              \
    float zt = bcast_lane63(z);                                               \
    float c = bcast_lane63(cp);                                               \
    float s2n = bcast_lane63(sp);                                             \
    __builtin_amdgcn_sched_barrier(0);                                        \
    {                                                                         \
      const v4f* _kv = (const v4f*)_kb;                                       \
      _Pragma("unroll")                                                       \
      for (int q = 8; q < 16; ++q) K2[q] = _kv[q]; /* late half */            \
    }                                                                         \
    float rn = 1.0f / (s2n + EPS);                                            \
    float gu = (zt > 0.f) ? u : 0.f;        /* Hopfield gate */               \
    v4f guv = {gu, gu, gu, gu};                                               \
    _Pragma("unroll")                                                         \
    for (int q = 0; q < 16; ++q)            /* M += gu * k_t^T */             \
      m4[q] = __builtin_elementwise_fma(guv, Kc[q], m4[q]);                   \
    vp = fmaf(gu, c, a);                    /* = M_{t+1} k_{t+1} */           \
    s2 = s2n; r = rn; ksc = ksn; ksn = ks2;                                   \
  } while (0)

// One block = one 64-lane wave = one batch chain. Lane i owns row i of M.
__global__ __launch_bounds__(64, 1)
void delta_mem_seq(const float* __restrict__ h,
                   const float* __restrict__ W,
                   const float* __restrict__ bias,
                   float* __restrict__ out,
                   int L) {
  const int b = blockIdx.x;
  const int lane = threadIdx.x;
  __shared__ float kring[8][64];
  __shared__ float rbuf[64];
  const float* __restrict__ hb = h + (size_t)b * (size_t)L * 64;
  const int LM1 = L - 1;

  v4f m4[16];
#pragma unroll
  for (int q = 0; q < 16; ++q) m4[q] = v4f{0.f, 0.f, 0.f, 0.f};

  // Prologue: 6 loads in flight (k_0..k_5), then pull k_0/k_1 to registers.
#pragma unroll
  for (int i = 0; i < 6; ++i) {
    int idx = (i <= LM1) ? i : LM1;
    GLL(idx, i);
  }
  asm volatile("s_waitcnt vmcnt(4)" ::: "memory");  // k_0, k_1 landed

  v4f KA[16], KB[16], KC[16];
  float ksc = kring[0][lane];
  float ksn = kring[1][lane];
  {
    const v4f* k0 = (const v4f*)&kring[0][0];
    const v4f* k1 = (const v4f*)&kring[1][0];
#pragma unroll
    for (int q = 0; q < 16; ++q) { KA[q] = k0[q]; KB[q] = k1[q]; }
  }
  float s2;
  {
    float t0 = ksc * ksc;
    WAVE_RED1(t0);
    s2 = bcast_lane63(t0);
  }
  float r = 1.0f / (s2 + EPS);
  float vp = 0.f;  // M_0 k_0 = 0

  int t = 0;
  while (t + 2 < LM1) {  // 3x unrolled role rotation of the K banks
    BODY(t, KA, KB, KC);
    BODY(t + 1, KB, KC, KA);
    BODY(t + 2, KC, KA, KB);
    t += 3;
  }
  if (t < LM1) { BODY(t, KA, KB, KC); ++t; }
  if (t < LM1) { BODY(t, KB, KC, KA); ++t; }

  // vp now IS read = M_final @ h[:, L-1]
  rbuf[lane] = vp;
  __syncthreads();

  // out[b][o] = sum_i W[o][i]*read[i] + bias[o]
  const v4f* wv = (const v4f*)(W + lane * 64);
  const v4f* rv = (const v4f*)rbuf;
  v4f acc = v4f{0.f, 0.f, 0.f, 0.f};
#pragma unroll
  for (int q = 0; q < 16; ++q)
    acc = __builtin_elementwise_fma(wv[q], rv[q], acc);
  out[(size_t)b * 64 + lane] =
      bias[lane] + ((acc.x + acc.y) + (acc.z + acc.w));
}

extern "C" void kernel_launch(void* const* d_in, const int* in_sizes, int n_in,
                              void* d_out, int out_size, void* d_ws, size_t ws_size,
                              hipStream_t stream) {
  const float* h    = (const float*)d_in[0];
  const float* W    = (const float*)d_in[1];
  const float* bias = (const float*)d_in[2];
  float* out = (float*)d_out;

  const int H = in_sizes[2];            // 64
  const int B = out_size / H;           // 256
  const int L = in_sizes[0] / (B * H);  // 2048

  delta_mem_seq<<<B, 64, 0, stream>>>(h, W, bias, out, L);
}

// Round 4
// 1235.470 us; speedup vs baseline: 1.5940x; 1.5940x over previous
//
#include <hip/hip_runtime.h>

typedef float v4f __attribute__((ext_vector_type(4)));

static constexpr float EPS = 1e-6f;

// DPP partial-sum step: x += dpp_move(x); out-of-bounds lanes contribute 0.
#define DPP_ADD(x, ctrl, rmask)                                               \
  x += __builtin_bit_cast(float, __builtin_amdgcn_update_dpp(                 \
           0, __builtin_bit_cast(int, x), ctrl, rmask, 0xf, true))

// Full wave64 sum, 3 values interleaved (fills DPP latency slots).
// After this, lane 63 holds each total.
#define WAVE_RED3(a, b, c)                                                    \
  do {                                                                        \
    DPP_ADD(a, 0x111, 0xf); DPP_ADD(b, 0x111, 0xf); DPP_ADD(c, 0x111, 0xf);  \
    DPP_ADD(a, 0x112, 0xf); DPP_ADD(b, 0x112, 0xf); DPP_ADD(c, 0x112, 0xf);  \
    DPP_ADD(a, 0x114, 0xf); DPP_ADD(b, 0x114, 0xf); DPP_ADD(c, 0x114, 0xf);  \
    DPP_ADD(a, 0x118, 0xf); DPP_ADD(b, 0x118, 0xf); DPP_ADD(c, 0x118, 0xf);  \
    DPP_ADD(a, 0x142, 0xa); DPP_ADD(b, 0x142, 0xa); DPP_ADD(c, 0x142, 0xa);  \
    DPP_ADD(a, 0x143, 0xc); DPP_ADD(b, 0x143, 0xc); DPP_ADD(c, 0x143, 0xc);  \
  } while (0)

#define WAVE_RED1(a)                                                          \
  do {                                                                        \
    DPP_ADD(a, 0x111, 0xf); DPP_ADD(a, 0x112, 0xf); DPP_ADD(a, 0x114, 0xf);  \
    DPP_ADD(a, 0x118, 0xf); DPP_ADD(a, 0x142, 0xa); DPP_ADD(a, 0x143, 0xc);  \
  } while (0)

__device__ __forceinline__ float rl63(float x) {
  return __builtin_bit_cast(
      float, __builtin_amdgcn_readlane(__builtin_bit_cast(int, x), 63));
}

#define GLL(idx, slot)                                                        \
  __builtin_amdgcn_global_load_lds(                                           \
      (const __attribute__((address_space(1))) void*)(hb + (size_t)(idx) * 64 + lane), \
      (__attribute__((address_space(3))) void*)&kring[(slot)][0], 4, 0, 0)

// STEP(KA, KB): KA = broadcast k_t (consumed by M-update THIS step, then
// overwritten by the k_{t+2} prefetch), KB = broadcast k_{t+1} (consumed by
// the a-dot THIS step; was prefetched at the END of the previous step, so its
// LDS latency hides under this step's front + RED3).
// Critical path: vp -> u -> z -> RED3 -> readlane -> gate -> vp'.
// Shadow work: a-dot (after RED3 in program order so its lgkmcnt wait cannot
// stall the reduction), M-update, reciprocal, prefetches.
#define STEP(KA, KB)                                                          \
  do {                                                                        \
    float u = fmaf(-vp, r, ksc);            /* u = k_t - vp/denom */          \
    float z = u * fmaf(s2, u, 2.0f * vp);   /* gate summand */                \
    float cp_ = ksc * ksn;                  /* -> k_t . k_{t+1} */            \
    float sp_ = ksn * ksn;                  /* -> |k_{t+1}|^2 */              \
    WAVE_RED3(z, cp_, sp_);                                                   \
    /* a = M_t . k_{t+1}; KB prefetched last step, latency covered by RED3 */ \
    v4f ac0 = v4f{0.f, 0.f, 0.f, 0.f}, ac1 = ac0, ac2 = ac0, ac3 = ac0;      \
    _Pragma("unroll")                                                         \
    for (int q = 0; q < 4; ++q) {                                             \
      ac0 = __builtin_elementwise_fma(m4[4 * q + 0], KB[4 * q + 0], ac0);     \
      ac1 = __builtin_elementwise_fma(m4[4 * q + 1], KB[4 * q + 1], ac1);     \
      ac2 = __builtin_elementwise_fma(m4[4 * q + 2], KB[4 * q + 2], ac2);     \
      ac3 = __builtin_elementwise_fma(m4[4 * q + 3], KB[4 * q + 3], ac3);     \
    }                                                                         \
    v4f acs = (ac0 + ac1) + (ac2 + ac3);                                      \
    float a = (acs.x + acs.y) + (acs.z + acs.w);                              \
    float zt = rl63(z);                                                       \
    float c = rl63(cp_);                                                      \
    float s2n = rl63(sp_);                                                    \
    float gu = (zt > 0.f) ? u : 0.f;        /* Hopfield gate */               \
    float vpn = fmaf(gu, c, a);             /* vp' = M_{t+1} k_{t+1} */       \
    v4f guv = {gu, gu, gu, gu};                                               \
    _Pragma("unroll")                                                         \
    for (int q = 0; q < 16; ++q)            /* M += gu * k_t^T */             \
      m4[q] = __builtin_elementwise_fma(guv, KA[q], m4[q]);                   \
    /* ring maintenance + next-next broadcast prefetch (KA now free) */       \
    {                                                                         \
      int _i8 = t + 8;                                                        \
      if (_i8 > LM1) _i8 = LM1;                                               \
      GLL(_i8, (t + 8) & 7);                                                  \
      asm volatile("s_waitcnt vmcnt(5)" ::: "memory"); /* k_{t+2} in LDS */   \
      const float* _kb = &kring[(t + 2) & 7][0];                              \
      float ks2 = _kb[lane];                                                  \
      const v4f* _kv = (const v4f*)_kb;                                       \
      _Pragma("unroll")                                                       \
      for (int q = 0; q < 16; ++q) KA[q] = _kv[q];                            \
      __builtin_amdgcn_sched_barrier(0);    /* pin prefetch: no sinking */    \
      ksc = ksn;                                                              \
      ksn = ks2;                                                              \
    }                                                                         \
    s2 = s2n;                                                                 \
    r = 1.0f / (s2n + EPS);                 /* off critical path */           \
    vp = vpn;                                                                 \
    ++t;                                                                      \
  } while (0)

// One block = one 64-lane wave = one batch chain. Lane i owns row i of M.
__global__ __launch_bounds__(64, 1)
void delta_mem_seq(const float* __restrict__ h,
                   const float* __restrict__ W,
                   const float* __restrict__ bias,
                   float* __restrict__ out,
                   int L) {
  const int b = blockIdx.x;
  const int lane = threadIdx.x;
  __shared__ float kring[8][64];
  __shared__ float rbuf[64];
  const float* __restrict__ hb = h + (size_t)b * (size_t)L * 64;
  const int LM1 = L - 1;

  v4f m4[16];
#pragma unroll
  for (int q = 0; q < 16; ++q) m4[q] = v4f{0.f, 0.f, 0.f, 0.f};

  // Prologue: fill the 8-slot ring (k_0..k_7), 6-deep steady state.
#pragma unroll
  for (int i = 0; i < 8; ++i) {
    int idx = (i <= LM1) ? i : LM1;
    GLL(idx, i);
  }
  asm volatile("s_waitcnt vmcnt(6)" ::: "memory");  // k_0, k_1 landed

  v4f KA[16], KB[16];
  float ksc = kring[0][lane];
  float ksn = kring[1][lane];
  {
    const v4f* k0 = (const v4f*)&kring[0][0];
    const v4f* k1 = (const v4f*)&kring[1][0];
#pragma unroll
    for (int q = 0; q < 16; ++q) { KA[q] = k0[q]; KB[q] = k1[q]; }
  }
  float s2;
  {
    float t0 = ksc * ksc;
    WAVE_RED1(t0);
    s2 = rl63(t0);
  }
  float r = 1.0f / (s2 + EPS);
  float vp = 0.f;  // M_0 k_0 = 0

  int t = 0;
  while (t + 1 < LM1) {  // ping-pong bank roles, 2x unroll
    STEP(KA, KB);
    STEP(KB, KA);
  }
  if (t < LM1) STEP(KA, KB);

  // vp now IS read = M_final @ h[:, L-1]
  rbuf[lane] = vp;
  __syncthreads();

  // out[b][o] = sum_i W[o][i]*read[i] + bias[o]   (lane = o, W row contiguous)
  const v4f* wv = (const v4f*)(W + lane * 64);
  const v4f* rv = (const v4f*)rbuf;
  v4f acc = v4f{0.f, 0.f, 0.f, 0.f};
#pragma unroll
  for (int q = 0; q < 16; ++q)
    acc = __builtin_elementwise_fma(wv[q], rv[q], acc);
  out[(size_t)b * 64 + lane] =
      bias[lane] + ((acc.x + acc.y) + (acc.z + acc.w));
}

extern "C" void kernel_launch(void* const* d_in, const int* in_sizes, int n_in,
                              void* d_out, int out_size, void* d_ws, size_t ws_size,
                              hipStream_t stream) {
  const float* h    = (const float*)d_in[0];
  const float* W    = (const float*)d_in[1];
  const float* bias = (const float*)d_in[2];
  float* out = (float*)d_out;

  const int H = in_sizes[2];            // 64
  const int B = out_size / H;           // 256
  const int L = in_sizes[0] / (B * H);  // 2048

  delta_mem_seq<<<B, 64, 0, stream>>>(h, W, bias, out, L);
}